// Round 8
// baseline (2163.490 us; speedup 1.0000x reference)
//
#include <hip/hip_runtime.h>

#define TT 2048
#define FF 12
#define NB 16
#define CHK 64
#define L2E 1.44269504088896340736f

typedef __attribute__((ext_vector_type(8))) short bf16x8;
typedef __attribute__((ext_vector_type(4))) float f32x4;

__device__ __forceinline__ float fast_exp2(float x){ return __builtin_amdgcn_exp2f(x); }
__device__ __forceinline__ float fast_rcp(float x){ return __builtin_amdgcn_rcpf(x); }
__device__ __forceinline__ unsigned short f2b(float x){
  unsigned u = __float_as_uint(x);
  return (unsigned short)((u + 0x7FFFu + ((u>>16)&1u)) >> 16);   // RNE fp32->bf16
}
__device__ __forceinline__ float sigf(float z){
  return fast_rcp(1.f + fast_exp2((-L2E)*z));                    // 1/(1+e^-z)
}
__device__ __forceinline__ float tanh2(float z){
  return fmaf(2.f, fast_rcp(1.f + fast_exp2((-2.f*L2E)*z)), -1.f); // 2*sig(2z)-1, saturates cleanly
}

// 16 blocks x 512 threads; block handles 16 batch elements via MFMA N-dim.
// Gate matvec: D(384x16) = W(384x128,bf16) * V(128x16,bf16), V col n = element n's
// v=[h(96)|x(21)|0]. W rows interleaved r=4u+gate so the verified D layout
// (col=lane&15, row=(lane>>4)*4+reg) gives each lane all 4 gates of unit
// u=4mt+(lane>>4) for element n=lane&15 -> c/h update fully lane-local.
// 24 M-tiles over 8 waves (3 each), 4 K-tiles; x = K-tile 3, pre-staged per
// chunk in B-fragment layout (xprep) -> zero per-step x work. h double-buffered
// bf16 in B-layout (17-padded vs bank aliasing). ONE barrier per step.
// c, h, lastk, h_fin stay fp32 in registers/LDS.
__global__ __launch_bounds__(512, 1) void lstm_mfma(
  const float* __restrict__ seq, const int* __restrict__ ev, const int* __restrict__ rsi,
  const int* __restrict__ len, const float* __restrict__ eemb, const float* __restrict__ remb,
  const float* __restrict__ W_ih, const float* __restrict__ W_hh,
  const float* __restrict__ b_ih, const float* __restrict__ b_hh,
  const float* __restrict__ W_mlp, const float* __restrict__ b_mlp,
  const float* __restrict__ W_fc, const float* __restrict__ b_fc,
  float* __restrict__ out)
{
  const int tid = threadIdx.x;
  const int wv  = tid >> 6;      // wave 0..7
  const int l   = tid & 63;
  const int lg  = l >> 4;        // lane group 0..3
  const int n   = l & 15;        // element column
  const int b16 = blockIdx.x * NB;

  __shared__ __align__(16) unsigned short vbuf[2][12][17][8]; // [p][kt8][n(+pad)][j] bf16 h rows k=0..95
  __shared__ __align__(16) unsigned short xprep[CHK][4][16][8]; // [r][kt8-12][n][j] bf16 x rows k=96..127
  __shared__ __align__(16) float lastk[NB][3][96];
  __shared__ __align__(16) float hfin[NB][96];
  __shared__ __align__(16) float hlk[NB][96];
  __shared__ __align__(16) float et[192];
  __shared__ __align__(16) float rt[24];
  __shared__ int evs[NB][CHK];
  __shared__ int rss[NB][CHK];

  // ---- prologue: A-fragments (weights) in registers ----
  // A: lane l supplies row m=16*mt+(l&15), k=32*kt+8*lg+j  (same slot->k map as B)
  bf16x8 Afr[3][4];
  #pragma unroll
  for (int jt = 0; jt < 3; ++jt) {
    const int mt = 3*wv + jt;
    const int m  = 16*mt + n;
    const int grow = (m & 3)*96 + (m >> 2);      // r=4u+gate -> original gate row
    #pragma unroll
    for (int kt = 0; kt < 4; ++kt) {
      bf16x8 a;
      #pragma unroll
      for (int j = 0; j < 8; ++j) {
        const int k = 32*kt + 8*lg + j;
        const float w = (k < 96) ? W_hh[grow*96 + k]
                      : ((k < 117) ? W_ih[grow*21 + (k-96)] : 0.f);
        a[j] = (short)f2b(w);
      }
      Afr[jt][kt] = a;
    }
  }
  // biases for the 3 units this lane updates
  float bias[3][4];
  int   uns[3];
  #pragma unroll
  for (int jt = 0; jt < 3; ++jt) {
    const int u = 4*(3*wv + jt) + lg;
    uns[jt] = u;
    #pragma unroll
    for (int g = 0; g < 4; ++g) bias[jt][g] = b_ih[g*96 + u] + b_hh[g*96 + u];
  }
  const int Ln = len[b16 + n];                   // this lane's element length
  int maxL = 0;
  #pragma unroll
  for (int j = 0; j < NB; ++j) maxL = max(maxL, len[b16 + j]);

  float c_reg[3] = {0.f, 0.f, 0.f};
  float h_reg[3] = {0.f, 0.f, 0.f};

  for (int i = tid; i < 2*12*17*8; i += 512) ((unsigned short*)vbuf)[i] = 0;
  for (int i = tid; i < NB*3*96;   i += 512) ((float*)lastk)[i] = 0.f;
  if (tid < 192) et[tid] = eemb[tid];
  if (tid < 24)  rt[tid] = remb[tid];

  for (int t0 = 0; t0 < maxL; t0 += CHK) {
    // ---- stage indices ----
    for (int i = tid; i < NB*CHK; i += 512) {
      const int nn = i >> 6, rr = i & (CHK-1);
      evs[nn][rr] = ev [(b16+nn)*TT + t0 + rr];
      rss[nn][rr] = rsi[(b16+nn)*TT + t0 + rr];
    }
    __syncthreads();
    // ---- fill xprep: B-fragment layout for k=96..127 ----
    for (int i = tid; i < CHK*512; i += 512) {
      const int j  = i & 7;
      const int n2 = (i >> 3) & 15;
      const int g4 = (i >> 7) & 3;
      const int r  = i >> 9;
      const int c  = 8*g4 + j;                 // x col 0..31 (real: 0..20)
      float v = 0.f;
      if      (c < 12) v = seq[(size_t)(b16+n2)*(TT*FF) + (size_t)(t0+r)*FF + c];
      else if (c < 18) v = et[evs[n2][r]*6 + (c-12)];
      else if (c < 21) v = rt[rss[n2][r]*3 + (c-18)];
      xprep[r][g4][n2][j] = f2b(v);
    }
    __syncthreads();

    const int nr = min(CHK, maxL - t0);
    for (int r = 0; r < nr; ++r) {
      const int p = (t0 + r) & 1;
      // ---- B fragments: 3x h (double-buffered) + 1x x (pre-staged) ----
      bf16x8 B0 = *(const bf16x8*)&vbuf[p][lg    ][n][0];
      bf16x8 B1 = *(const bf16x8*)&vbuf[p][4+lg  ][n][0];
      bf16x8 B2 = *(const bf16x8*)&vbuf[p][8+lg  ][n][0];
      bf16x8 B3 = *(const bf16x8*)&xprep[r][lg][n][0];
      // ---- 12 MFMAs: 3 M-tiles x 4 K-tiles ----
      f32x4 acc[3];
      #pragma unroll
      for (int jt = 0; jt < 3; ++jt) {
        f32x4 a = {0.f, 0.f, 0.f, 0.f};
        a = __builtin_amdgcn_mfma_f32_16x16x32_bf16(Afr[jt][0], B0, a, 0, 0, 0);
        a = __builtin_amdgcn_mfma_f32_16x16x32_bf16(Afr[jt][1], B1, a, 0, 0, 0);
        a = __builtin_amdgcn_mfma_f32_16x16x32_bf16(Afr[jt][2], B2, a, 0, 0, 0);
        a = __builtin_amdgcn_mfma_f32_16x16x32_bf16(Afr[jt][3], B3, a, 0, 0, 0);
        acc[jt] = a;
      }
      // ---- lane-local update: unit uns[jt], element n ----
      const int t = t0 + r;
      const bool act = t < Ln;
      #pragma unroll
      for (int jt = 0; jt < 3; ++jt) {
        const float zi = acc[jt][0] + bias[jt][0];
        const float zf = acc[jt][1] + bias[jt][1];
        const float zg = acc[jt][2] + bias[jt][2];
        const float zo = acc[jt][3] + bias[jt][3];
        const float cn = fmaf(sigf(zf), c_reg[jt], sigf(zi)*tanh2(zg));
        const float hn = sigf(zo) * tanh2(cn);
        if (act) { c_reg[jt] = cn; h_reg[jt] = hn; }
        const int u = uns[jt];
        vbuf[p^1][u >> 3][n][u & 7] = f2b(h_reg[jt]);
        const int kk = t + 3 - Ln;               // last-K ring: t in [Ln-3, Ln)
        if (kk >= 0 && kk < 3) lastk[n][kk][u] = hn;
      }
      __syncthreads();
    }
  }

  // ---- epilogue ----
  #pragma unroll
  for (int jt = 0; jt < 3; ++jt) hfin[n][uns[jt]] = h_reg[jt];
  __syncthreads();
  // h_lastk = relu(W_mlp @ lastk + b_mlp): 32 threads per element, 3 rows each
  {
    const int ne = tid >> 5;
    const int s  = tid & 31;
    const float* lk = &lastk[ne][0][0];          // 288 contiguous: [h(L-3)|h(L-2)|h(L-1)]
    for (int m = s; m < 96; m += 32) {
      const float* wrow = W_mlp + m*288;
      float a0 = 0.f, a1 = 0.f, a2 = 0.f;
      #pragma unroll 4
      for (int i = 0; i < 96; ++i) {
        a0 = fmaf(wrow[i],       lk[i],       a0);
        a1 = fmaf(wrow[96 + i],  lk[96 + i],  a1);
        a2 = fmaf(wrow[192 + i], lk[192 + i], a2);
      }
      hlk[ne][m] = fmaxf((a0 + a1) + a2 + b_mlp[m], 0.f);
    }
  }
  __syncthreads();
  if (tid < 32) {
    const int ne = tid >> 1;
    const int o  = tid & 1;
    const float* wf = W_fc + o*192;
    float a = b_fc[o];
    #pragma unroll 4
    for (int j = 0; j < 96; ++j) {
      a = fmaf(wf[j],      hfin[ne][j], a);
      a = fmaf(wf[96 + j], hlk[ne][j],  a);
    }
    out[(b16 + ne)*2 + o] = a;
  }
}

extern "C" void kernel_launch(void* const* d_in, const int* in_sizes, int n_in,
                              void* d_out, int out_size, void* d_ws, size_t ws_size,
                              hipStream_t stream) {
  const float* seq   = (const float*)d_in[0];
  const int*   ev    = (const int*)  d_in[1];
  const int*   rsi   = (const int*)  d_in[2];
  const int*   len   = (const int*)  d_in[3];
  const float* eemb  = (const float*)d_in[4];
  const float* remb  = (const float*)d_in[5];
  const float* W_ih  = (const float*)d_in[6];
  const float* W_hh  = (const float*)d_in[7];
  const float* b_ih  = (const float*)d_in[8];
  const float* b_hh  = (const float*)d_in[9];
  const float* W_mlp = (const float*)d_in[10];
  const float* b_mlp = (const float*)d_in[11];
  const float* W_fc  = (const float*)d_in[12];
  const float* b_fc  = (const float*)d_in[13];

  hipLaunchKernelGGL(lstm_mfma, dim3(16), dim3(512), 0, stream,
                     seq, ev, rsi, len, eemb, remb, W_ih, W_hh, b_ih, b_hh,
                     W_mlp, b_mlp, W_fc, b_fc, (float*)d_out);
}

// Round 9
// 1417.269 us; speedup vs baseline: 1.5265x; 1.5265x over previous
//
#include <hip/hip_runtime.h>

#define TT 2048
#define FF 12
#define NE 4            // elements per block
#define CHK 64
#define L2E 1.44269504088896340736f

typedef __attribute__((ext_vector_type(8))) short bf16x8;
typedef __attribute__((ext_vector_type(4))) float f32x4;

__device__ __forceinline__ float fast_exp2(float x){ return __builtin_amdgcn_exp2f(x); }
__device__ __forceinline__ float fast_rcp(float x){ return __builtin_amdgcn_rcpf(x); }
__device__ __forceinline__ unsigned short f2b(float x){
  unsigned u = __float_as_uint(x);
  return (unsigned short)((u + 0x7FFFu + ((u>>16)&1u)) >> 16);   // RNE fp32->bf16
}
__device__ __forceinline__ float sigf(float z){
  return fast_rcp(1.f + fast_exp2((-L2E)*z));                    // 1/(1+e^-z)
}
__device__ __forceinline__ float tanh2(float z){
  return fmaf(2.f, fast_rcp(1.f + fast_exp2((-2.f*L2E)*z)), -1.f); // 2*sig(2z)-1
}

#define DPPF(x, ctrl) __int_as_float(__builtin_amdgcn_update_dpp(0, __float_as_int(x), (ctrl), 0xF, 0xF, true))
#define SHR4 0x114   // row_shr:4 -> dst[i]=src[i-4]
#define SHR8 0x118   // row_shr:8 -> dst[i]=src[i-8]

// 64 blocks x 512 threads; block owns 4 batch elements (MFMA cols 0..3; cols
// 4..15 stay zero). Gate matvec D(384x16) = W(384x128,bf16) x V(128x16,bf16)
// exactly as R8 (HW-verified layout). After MFMA, lane (lg,n) holds
// acc[jt][g] = gate g of unit u=12wv+4jt+lg for col n. Redistribution: with
// e=n&3 (real elem), k=(n>>2)&3 (spare slot), row_shr:4/8 DPP moves acc[1],
// acc[2] from the k=0 lane so lane (lg,k<3,e) updates ONE unit u=12wv+4k+lg
// for elem e -> 10 trans-ops per wave per step instead of 30. MFMA chains
// split 2+2 (+vector add). ONE barrier per step. c,h,lastk,hfin stay fp32.
__global__ __launch_bounds__(512, 1) void lstm_mfma(
  const float* __restrict__ seq, const int* __restrict__ ev, const int* __restrict__ rsi,
  const int* __restrict__ len, const float* __restrict__ eemb, const float* __restrict__ remb,
  const float* __restrict__ W_ih, const float* __restrict__ W_hh,
  const float* __restrict__ b_ih, const float* __restrict__ b_hh,
  const float* __restrict__ W_mlp, const float* __restrict__ b_mlp,
  const float* __restrict__ W_fc, const float* __restrict__ b_fc,
  float* __restrict__ out)
{
  const int tid = threadIdx.x;
  const int wv  = tid >> 6;      // wave 0..7
  const int l   = tid & 63;
  const int lg  = l >> 4;        // lane group 0..3
  const int n   = l & 15;        // D column
  const int e   = n & 3;         // real element 0..3
  const int k   = (n >> 2) & 3;  // redistribution slot 0..3 (k<3 active)
  const int b4  = blockIdx.x * NE;

  __shared__ __align__(16) unsigned short vbuf[2][12][17][8];   // bf16 h, B-frag layout, cols 4..15 = 0
  __shared__ __align__(16) unsigned short xprep[CHK][4][16][8]; // bf16 x, B-frag layout, cols 4..15 = 0
  __shared__ __align__(16) float lastk[NE][3][96];
  __shared__ __align__(16) float hfin[NE][96];
  __shared__ __align__(16) float hlk[NE][96];
  __shared__ __align__(16) float et[192];
  __shared__ __align__(16) float rt[24];
  __shared__ int evs[NE][CHK];
  __shared__ int rss[NE][CHK];

  // ---- prologue: A-fragments (weights), HW-verified layout from R8 ----
  bf16x8 Afr[3][4];
  #pragma unroll
  for (int jt = 0; jt < 3; ++jt) {
    const int m    = 16*(3*wv + jt) + n;         // A row
    const int grow = (m & 3)*96 + (m >> 2);      // interleave r=4u+gate
    #pragma unroll
    for (int kt = 0; kt < 4; ++kt) {
      bf16x8 a;
      #pragma unroll
      for (int j = 0; j < 8; ++j) {
        const int kk = 32*kt + 8*lg + j;
        const float w = (kk < 96) ? W_hh[grow*96 + kk]
                      : ((kk < 117) ? W_ih[grow*21 + (kk-96)] : 0.f);
        a[j] = (short)f2b(w);
      }
      Afr[jt][kt] = a;
    }
  }
  // bias for this lane's post-redistribute unit
  const int ku = (k < 3) ? k : 0;
  const int u  = 12*wv + 4*ku + lg;              // owned unit (valid when k<3)
  float bias[4];
  #pragma unroll
  for (int g = 0; g < 4; ++g) bias[g] = b_ih[g*96 + u] + b_hh[g*96 + u];

  const int Ln = len[b4 + e];
  int maxL = 0;
  #pragma unroll
  for (int j = 0; j < NE; ++j) maxL = max(maxL, len[b4 + j]);

  float c_reg = 0.f, h_reg = 0.f;

  for (int i = tid; i < 2*12*17*8/2; i += 512) ((unsigned int*)vbuf)[i]  = 0u;
  for (int i = tid; i < CHK*4*16*8/2; i += 512) ((unsigned int*)xprep)[i] = 0u;
  for (int i = tid; i < NE*3*96; i += 512) ((float*)lastk)[i] = 0.f;
  if (tid < 192) et[tid] = eemb[tid];
  if (tid < 24)  rt[tid] = remb[tid];
  __syncthreads();                               // init drains before staging (R6 lesson)

  for (int t0 = 0; t0 < maxL; t0 += CHK) {
    // ---- stage indices ----
    for (int i = tid; i < NE*CHK; i += 512) {
      const int nn = i >> 6, rr = i & (CHK-1);
      evs[nn][rr] = ev [(b4+nn)*TT + t0 + rr];
      rss[nn][rr] = rsi[(b4+nn)*TT + t0 + rr];
    }
    __syncthreads();
    // ---- fill xprep cols 0..3 (B-frag layout, k-rows 96..127) ----
    for (int i = tid; i < CHK*NE*32; i += 512) {
      const int r   = i >> 7;
      const int rem = i & 127;
      const int n2  = rem >> 5;
      const int c   = rem & 31;
      float v = 0.f;
      if      (c < 12) v = seq[(size_t)(b4+n2)*(TT*FF) + (size_t)(t0+r)*FF + c];
      else if (c < 18) v = et[evs[n2][r]*6 + (c-12)];
      else if (c < 21) v = rt[rss[n2][r]*3 + (c-18)];
      xprep[r][c >> 3][n2][c & 7] = f2b(v);
    }
    __syncthreads();

    const int nr = min(CHK, maxL - t0);
    for (int r = 0; r < nr; ++r) {
      const int p = (t0 + r) & 1;
      // ---- B fragments ----
      bf16x8 B0 = *(const bf16x8*)&vbuf[p][lg    ][n][0];
      bf16x8 B1 = *(const bf16x8*)&vbuf[p][4+lg  ][n][0];
      bf16x8 B2 = *(const bf16x8*)&vbuf[p][8+lg  ][n][0];
      bf16x8 B3 = *(const bf16x8*)&xprep[r][lg][n][0];
      // ---- 12 MFMAs, 2+2 split chains ----
      f32x4 acc[3];
      #pragma unroll
      for (int jt = 0; jt < 3; ++jt) {
        f32x4 a1 = {0.f,0.f,0.f,0.f}, a2 = {0.f,0.f,0.f,0.f};
        a1 = __builtin_amdgcn_mfma_f32_16x16x32_bf16(Afr[jt][0], B0, a1, 0, 0, 0);
        a2 = __builtin_amdgcn_mfma_f32_16x16x32_bf16(Afr[jt][2], B2, a2, 0, 0, 0);
        a1 = __builtin_amdgcn_mfma_f32_16x16x32_bf16(Afr[jt][1], B1, a1, 0, 0, 0);
        a2 = __builtin_amdgcn_mfma_f32_16x16x32_bf16(Afr[jt][3], B3, a2, 0, 0, 0);
        acc[jt] = a1 + a2;
      }
      // ---- DPP redistribution: slot k gets acc[k] of the k=0 lane ----
      float z[4];
      #pragma unroll
      for (int g = 0; g < 4; ++g) {
        const float s4 = DPPF(acc[1][g], SHR4);
        const float s8 = DPPF(acc[2][g], SHR8);
        z[g] = (k == 0) ? acc[0][g] : ((k == 1) ? s4 : s8);
      }
      // ---- one unit update per lane ----
      const float zi = z[0] + bias[0];
      const float zf = z[1] + bias[1];
      const float zg = z[2] + bias[2];
      const float zo = z[3] + bias[3];
      const float cn = fmaf(sigf(zf), c_reg, sigf(zi)*tanh2(zg));
      const float hn = sigf(zo) * tanh2(cn);
      const int t = t0 + r;
      if (t < Ln) { c_reg = cn; h_reg = hn; }
      if (k < 3) {
        vbuf[p^1][u >> 3][e][u & 7] = f2b(h_reg);
        const int kk = t + 3 - Ln;               // last-K ring: t in [Ln-3, Ln)
        if (kk >= 0 && kk < 3) lastk[e][kk][u] = h_reg;
      }
      __syncthreads();
    }
  }

  // ---- epilogue ----
  if (k < 3) hfin[e][u] = h_reg;
  __syncthreads();
  if (tid < NE*96) {
    const int ne = tid / 96;
    const int m  = tid - ne*96;
    const float* wrow = W_mlp + m*288;
    const float* lk = &lastk[ne][0][0];          // 288 contiguous
    float a0 = 0.f, a1 = 0.f, a2 = 0.f;
    #pragma unroll 4
    for (int i = 0; i < 96; ++i) {
      a0 = fmaf(wrow[i],       lk[i],       a0);
      a1 = fmaf(wrow[96 + i],  lk[96 + i],  a1);
      a2 = fmaf(wrow[192 + i], lk[192 + i], a2);
    }
    hlk[ne][m] = fmaxf((a0 + a1) + a2 + b_mlp[m], 0.f);
  }
  __syncthreads();
  if (tid < NE*2) {
    const int ne = tid >> 1;
    const int o  = tid & 1;
    const float* wf = W_fc + o*192;
    float a = b_fc[o];
    #pragma unroll 4
    for (int j = 0; j < 96; ++j) {
      a = fmaf(wf[j],      hfin[ne][j], a);
      a = fmaf(wf[96 + j], hlk[ne][j],  a);
    }
    out[(b4 + ne)*2 + o] = a;
  }
}

extern "C" void kernel_launch(void* const* d_in, const int* in_sizes, int n_in,
                              void* d_out, int out_size, void* d_ws, size_t ws_size,
                              hipStream_t stream) {
  const float* seq   = (const float*)d_in[0];
  const int*   ev    = (const int*)  d_in[1];
  const int*   rsi   = (const int*)  d_in[2];
  const int*   len   = (const int*)  d_in[3];
  const float* eemb  = (const float*)d_in[4];
  const float* remb  = (const float*)d_in[5];
  const float* W_ih  = (const float*)d_in[6];
  const float* W_hh  = (const float*)d_in[7];
  const float* b_ih  = (const float*)d_in[8];
  const float* b_hh  = (const float*)d_in[9];
  const float* W_mlp = (const float*)d_in[10];
  const float* b_mlp = (const float*)d_in[11];
  const float* W_fc  = (const float*)d_in[12];
  const float* b_fc  = (const float*)d_in[13];

  hipLaunchKernelGGL(lstm_mfma, dim3(64), dim3(512), 0, stream,
                     seq, ev, rsi, len, eemb, remb, W_ih, W_hh, b_ih, b_hh,
                     W_mlp, b_mlp, W_fc, b_fc, (float*)d_out);
}